// Round 6
// baseline (214.179 us; speedup 1.0000x reference)
//
#include <hip/hip_runtime.h>

// VectorQuantizer gather: out[b][d][n] = embedding[indices[b][n]][d]
// B=32, N=4096 (64x64), K=1024, D=256. fp32 out = 128 MiB.
//
// v5 (resubmit after infra failure) = DIAGNOSTIC: v3 exactly, gridDim.y = 5.
//  Four structurally different kernels (scattered reads / line-exact reads /
//  write-retiled / nt stores) all show ~59 us of non-fill time, and the
//  kernel has never ranked in the profiled top-5, so its own counters have
//  never been visible. Each y-slice repeats identical work (same-value
//  concurrent stores are benign; output unchanged). HW traffic is 5x.
//  Pre-committed read:
//    dur ~ 142 + 4*K.  K=59 -> ~375 us (kernel slow; its FETCH_SIZE row
//    reveals whether stores pay RFO).  K=20 -> ~220 us (kernel already at
//    write roofline; residual is fixed harness work -> revert + ROOFLINE).

#define VQ_B 32
#define VQ_N 4096
#define VQ_D 256
#define DC 32            // d-chunk per block
#define NT 1024          // n-tile per block
#define NW 256           // n per wave
#define NSUB 32          // n per sub-iteration
#define TSTRIDE 34       // LDS tile row stride in floats (pad vs 32)
#define REP 5            // diagnostic replication factor (grid.y)

__global__ __launch_bounds__(256, 4) void vq_gather_kernel(
    const int* __restrict__ indices,
    const float* __restrict__ embedding,
    float* __restrict__ out)
{
    __shared__ int   s_idx[NT];
    __shared__ float s_tile[4][NSUB * TSTRIDE];   // per-wave transpose tile

    const int bid = blockIdx.x;
    const int nt  = bid & 3;          // n-tile 0..3
    const int dc  = (bid >> 2) & 7;   // d-chunk 0..7
    const int b   = bid >> 5;         // batch 0..31

    const int t = threadIdx.x;
    const int w = t >> 6;             // wave 0..3
    const int l = t & 63;

    // stage this block's 1024 indices (coalesced, one barrier total)
    #pragma unroll
    for (int k = 0; k < 4; ++k)
        s_idx[t + 256 * k] = indices[b * VQ_N + nt * NT + t + 256 * k];
    __syncthreads();

    // load-phase mapping: 8 lanes cover one 128 B row slice
    const int s  = l & 7;             // float4 slot within row slice
    const int nn = l >> 3;            // row-in-group 0..7
    // store-phase mapping: 8 lanes cover 32 n for one d
    const int ss = l & 7;             // n-quad 0..7
    const int dd = l >> 3;            // d-in-group 0..7

    float* tile = s_tile[w];
    const float* emb_c = embedding + dc * DC;     // column offset into rows
    const int wbase = w * NW;

    float* out_w = out + (b * VQ_D + dc * DC) * VQ_N + nt * NT + wbase;

    float4 v[4], vn[4];

    // prologue: gather sub-tile 0 (4 x float4 per lane = 32 rows x 128 B)
    #pragma unroll
    for (int k = 0; k < 4; ++k) {
        const int row = s_idx[wbase + nn + 8 * k];
        v[k] = ((const float4*)(emb_c + row * VQ_D))[s];
    }

    for (int si = 0; si < 8; ++si) {
        // prefetch next sub-tile's gathers (hide L2 latency under LDS+stores)
        if (si < 7) {
            #pragma unroll
            for (int k = 0; k < 4; ++k) {
                const int row = s_idx[wbase + (si + 1) * NSUB + nn + 8 * k];
                vn[k] = ((const float4*)(emb_c + row * VQ_D))[s];
            }
        }

        // transpose in: tile[n][d]
        #pragma unroll
        for (int k = 0; k < 4; ++k) {
            float* p = &tile[(nn + 8 * k) * TSTRIDE + 4 * s];
            p[0] = v[k].x; p[1] = v[k].y; p[2] = v[k].z; p[3] = v[k].w;
        }

        // transpose out: column reads -> float4 stores, 4 KB runs per d
        #pragma unroll
        for (int q = 0; q < 4; ++q) {
            const int d = dd + 8 * q;
            float4 o;
            o.x = tile[(4 * ss + 0) * TSTRIDE + d];
            o.y = tile[(4 * ss + 1) * TSTRIDE + d];
            o.z = tile[(4 * ss + 2) * TSTRIDE + d];
            o.w = tile[(4 * ss + 3) * TSTRIDE + d];
            *(float4*)(out_w + d * VQ_N + si * NSUB + 4 * ss) = o;
        }

        #pragma unroll
        for (int k = 0; k < 4; ++k) v[k] = vn[k];
    }
}

extern "C" void kernel_launch(void* const* d_in, const int* in_sizes, int n_in,
                              void* d_out, int out_size, void* d_ws, size_t ws_size,
                              hipStream_t stream) {
    const int*   indices   = (const int*)d_in[0];    // (32,1,4096) int32
    const float* embedding = (const float*)d_in[1];  // (1024,256) fp32
    float* out = (float*)d_out;                      // (32,256,64,64) fp32

    vq_gather_kernel<<<dim3(VQ_B * 8 * 4, REP), dim3(256), 0, stream>>>(
        indices, embedding, out);
}

// Round 7
// 141.572 us; speedup vs baseline: 1.5129x; 1.5129x over previous
//
#include <hip/hip_runtime.h>

// VectorQuantizer gather: out[b][d][n] = embedding[indices[b][n]][d]
// B=32, N=4096 (64x64), K=1024, D=256. fp32 out = 128 MiB -> write-BW bound.
//
// v6 = v3 with the REP=5 diagnostic removed. FINAL.
//  Diagnostic result (v5, grid.y=5): kernel's own counters showed
//  WRITE_SIZE = 5 x 134 MB exact, FETCH_SIZE ~7.6 MB (no RFO; embedding
//  L2-resident), 6.35 TB/s = 79-80% of peak == the device fill's own
//  achievable ceiling. Kernel is at the write-BW roofline (~21 us/replica);
//  the rest of the benched 140 us is the harness's 512 MiB poison fill
//  (~81 us) + fixed small dispatches + single-dispatch launch/ramp.
//
//  Structure: block = (b, 32-d chunk, 1024-n tile); line-exact 128 B
//  embedding row-slice reads (8 lanes/line, 100% consumption); per-wave
//  private LDS transpose tiles [32][34] (no main-loop barriers); register
//  double-buffered gathers; float4 stores in 4 KB contiguous runs per d.

#define VQ_B 32
#define VQ_N 4096
#define VQ_D 256
#define DC 32            // d-chunk per block
#define NT 1024          // n-tile per block
#define NW 256           // n per wave
#define NSUB 32          // n per sub-iteration
#define TSTRIDE 34       // LDS tile row stride in floats (pad vs 32)

__global__ __launch_bounds__(256, 4) void vq_gather_kernel(
    const int* __restrict__ indices,
    const float* __restrict__ embedding,
    float* __restrict__ out)
{
    __shared__ int   s_idx[NT];
    __shared__ float s_tile[4][NSUB * TSTRIDE];   // per-wave transpose tile

    const int bid = blockIdx.x;
    const int nt  = bid & 3;          // n-tile 0..3
    const int dc  = (bid >> 2) & 7;   // d-chunk 0..7
    const int b   = bid >> 5;         // batch 0..31

    const int t = threadIdx.x;
    const int w = t >> 6;             // wave 0..3
    const int l = t & 63;

    // stage this block's 1024 indices (coalesced, one barrier total)
    #pragma unroll
    for (int k = 0; k < 4; ++k)
        s_idx[t + 256 * k] = indices[b * VQ_N + nt * NT + t + 256 * k];
    __syncthreads();

    // load-phase mapping: 8 lanes cover one 128 B row slice
    const int s  = l & 7;             // float4 slot within row slice
    const int nn = l >> 3;            // row-in-group 0..7
    // store-phase mapping: 8 lanes cover 32 n for one d
    const int ss = l & 7;             // n-quad 0..7
    const int dd = l >> 3;            // d-in-group 0..7

    float* tile = s_tile[w];
    const float* emb_c = embedding + dc * DC;     // column offset into rows
    const int wbase = w * NW;

    float* out_w = out + (b * VQ_D + dc * DC) * VQ_N + nt * NT + wbase;

    float4 v[4], vn[4];

    // prologue: gather sub-tile 0 (4 x float4 per lane = 32 rows x 128 B)
    #pragma unroll
    for (int k = 0; k < 4; ++k) {
        const int row = s_idx[wbase + nn + 8 * k];
        v[k] = ((const float4*)(emb_c + row * VQ_D))[s];
    }

    for (int si = 0; si < 8; ++si) {
        // prefetch next sub-tile's gathers (hide L2 latency under LDS+stores)
        if (si < 7) {
            #pragma unroll
            for (int k = 0; k < 4; ++k) {
                const int row = s_idx[wbase + (si + 1) * NSUB + nn + 8 * k];
                vn[k] = ((const float4*)(emb_c + row * VQ_D))[s];
            }
        }

        // transpose in: tile[n][d]
        #pragma unroll
        for (int k = 0; k < 4; ++k) {
            float* p = &tile[(nn + 8 * k) * TSTRIDE + 4 * s];
            p[0] = v[k].x; p[1] = v[k].y; p[2] = v[k].z; p[3] = v[k].w;
        }

        // transpose out: column reads -> float4 stores, 4 KB runs per d
        #pragma unroll
        for (int q = 0; q < 4; ++q) {
            const int d = dd + 8 * q;
            float4 o;
            o.x = tile[(4 * ss + 0) * TSTRIDE + d];
            o.y = tile[(4 * ss + 1) * TSTRIDE + d];
            o.z = tile[(4 * ss + 2) * TSTRIDE + d];
            o.w = tile[(4 * ss + 3) * TSTRIDE + d];
            *(float4*)(out_w + d * VQ_N + si * NSUB + 4 * ss) = o;
        }

        #pragma unroll
        for (int k = 0; k < 4; ++k) v[k] = vn[k];
    }
}

extern "C" void kernel_launch(void* const* d_in, const int* in_sizes, int n_in,
                              void* d_out, int out_size, void* d_ws, size_t ws_size,
                              hipStream_t stream) {
    const int*   indices   = (const int*)d_in[0];    // (32,1,4096) int32
    const float* embedding = (const float*)d_in[1];  // (1024,256) fp32
    float* out = (float*)d_out;                      // (32,256,64,64) fp32

    vq_gather_kernel<<<dim3(VQ_B * 8 * 4), dim3(256), 0, stream>>>(
        indices, embedding, out);
}